// Round 8
// baseline (226.814 us; speedup 1.0000x reference)
//
#include <hip/hip_runtime.h>
#include <hip/hip_bf16.h>

// Problem constants
#define NB 2
#define SS 2048
#define EE 1024
#define HH 16
#define DD 64
#define NHD (NB*HH)   // 32 (n,h) pairs
#define KT 64         // keys per flash tile

// fold softmax scale (1/sqrt(1024)) and log2(e) into Q' so P = exp2(S')
#define QSCALE 0.04508422002777998f

typedef _Float16 half8 __attribute__((ext_vector_type(8)));
typedef float floatx4 __attribute__((ext_vector_type(4)));
typedef float floatx16 __attribute__((ext_vector_type(16)));

__device__ __forceinline__ half8 cvt8(const float* p) {
    float4 x = *(const float4*)p;
    float4 y = *(const float4*)(p + 4);
    half8 h = { (_Float16)x.x, (_Float16)x.y, (_Float16)x.z, (_Float16)x.w,
                (_Float16)y.x, (_Float16)y.y, (_Float16)y.z, (_Float16)y.w };
    return h;
}

// packed f32x2 -> f16x2 (RTZ) returning raw u32
__device__ __forceinline__ unsigned int pkrtz_u32(float a, float b) {
    return __builtin_bit_cast(unsigned int, __builtin_amdgcn_cvt_pkrtz(a, b));
}

// XOR-swizzled index (in halves) for [R][64-half] f16 LDS tiles (R<=128).
// 16B groups: group' = group ^ (row&7). Keeps b128 alignment (r13-verified).
__device__ __forceinline__ int swz64(int row, int colh) {
    return (row << 6) + ((((colh >> 3) ^ (row & 7)) << 3) | (colh & 7));
}

// ---------------------------------------------------------------------------
// Kernel 1 (r17, unchanged): QKV projection via MFMA + absorbed Wo f32->f16.
// All outputs route through the swizzled LDS tile -> 128B-line stores.
// Outputs: Q' f16 [nh][s][d] pre-scaled, K' f16 [nh][s][d], V' f16 [nh][d][s],
//          Wf f16 [1024][1024].
// ---------------------------------------------------------------------------
__global__ __launch_bounds__(256) void proj_kernel(
    const float* __restrict__ Q, const float* __restrict__ K, const float* __restrict__ V,
    const float* __restrict__ Wq, const float* __restrict__ Wk, const float* __restrict__ Wv,
    const float* __restrict__ Wo,
    _Float16* __restrict__ Qp, _Float16* __restrict__ Kp, _Float16* __restrict__ Vt,
    _Float16* __restrict__ Wf)
{
    int t = threadIdx.x, lane = t & 63, wid = t >> 6;
    int lr = lane & 15, lg = lane >> 4;
    int b = blockIdx.x;             // 0..1023
    int nh = b >> 5, st = b & 31;   // head-pair, s-tile (64 rows)
    int n = nh >> 4, h = nh & 15;

    // absorbed wconv: 128 threads x 8 elems = 1KB of Wo per block
    if (t < 128) {
        int i = b * 1024 + t * 8;
        *(half8*)(Wf + i) = cvt8(Wo + i);
    }

    __shared__ __align__(16) _Float16 vt[64 * 64];   // 8 KB, swizzled

    // A-fragment rows: s = st*64 + wid*16 + lr  (m = lane&15)
    const size_t xoff = ((size_t)n * SS + st * 64 + wid * 16 + lr) * EE
                        + (size_t)h * DD + lg * 8;

    // coalesced output map: thread t covers row t>>2, 2x16B at col (t&3)*16
    int orow = t >> 2, ocol = (t & 3) * 16;
    _Float16* qdst = Qp + ((size_t)nh * SS + st * 64 + orow) * DD + ocol;
    _Float16* kdst = Kp + ((size_t)nh * SS + st * 64 + orow) * DD + ocol;
    _Float16* vdst = Vt + ((size_t)nh * DD + orow) * SS + st * 64 + ocol;

    const float* tens[3] = {Q, K, V};
    const float* wts[3]  = {Wq, Wk, Wv};

    #pragma unroll
    for (int x = 0; x < 3; ++x) {
        const float* Xr = tens[x] + xoff;
        half8 a0 = cvt8(Xr);
        half8 a1 = cvt8(Xr + 32);
        floatx4 acc[4];
        #pragma unroll
        for (int ns = 0; ns < 4; ++ns) {
            const float* Wr = wts[x] + (size_t)(ns * 16 + lr) * DD + lg * 8;
            half8 b0 = cvt8(Wr);
            half8 b1 = cvt8(Wr + 32);
            floatx4 c = (floatx4){0.f, 0.f, 0.f, 0.f};
            c = __builtin_amdgcn_mfma_f32_16x16x32_f16(a0, b0, c, 0, 0, 0);
            c = __builtin_amdgcn_mfma_f32_16x16x32_f16(a1, b1, c, 0, 0, 0);
            acc[ns] = c;
        }
        if (x) __syncthreads();   // previous pass's vt reads done
        if (x < 2) {
            // Q/K: vt[s_local][d], s_local = wid*16+lg*4+r, d = ns*16+lr
            float s = (x == 0) ? QSCALE : 1.0f;
            #pragma unroll
            for (int ns = 0; ns < 4; ++ns)
                #pragma unroll
                for (int r = 0; r < 4; ++r)
                    vt[swz64(wid * 16 + lg * 4 + r, ns * 16 + lr)]
                        = (_Float16)(acc[ns][r] * s);
        } else {
            // V transpose: vt[d][s_local]
            #pragma unroll
            for (int ns = 0; ns < 4; ++ns)
                #pragma unroll
                for (int r = 0; r < 4; ++r)
                    vt[swz64(ns * 16 + lr, wid * 16 + lg * 4 + r)]
                        = (_Float16)(acc[ns][r]);
        }
        __syncthreads();
        _Float16* dst = (x == 0) ? qdst : (x == 1) ? kdst : vdst;
        *(half8*)dst       = *(const half8*)(&vt[swz64(orow, ocol)]);
        *(half8*)(dst + 8) = *(const half8*)(&vt[swz64(orow, ocol + 8)]);
    }
}

// ---------------------------------------------------------------------------
// Kernel 2 (r19): flash MFMA attention, 32x32 MFMA + in-register P.
// BISECT of r18's accuracy failure: keep the unified-smem + hoisted-offset
// structure (verified address-identical to r17), RESTORE r17 numerics:
// exp2f(fminf(.,50)) and exact 1.f/ divide. (r18's exp2 builtin was a
// numeric no-op anyway - OCML exp2_f32 IS v_exp_f32 - so the only true
// numeric deltas were clamp-removal and rcp; this isolates them.)
// ALSO: launched as TWO half-grids (bofs 0/256) so each dispatch ~36us
// drops BELOW proj/oproj -> they surface in next round's rocprof top-5.
// 32x32 frag maps (r16-verified): A/B[m][k]: m=lane&31, k=(lane>>5)*8+j.
// C/D: col=lane&31, row=(r&3)+8*(r>>2)+4*(lane>>5).
// GRID: 2 x 256 = 32 nh x 16 q-tiles (128 rows). LDS 32KB -> 2 blocks/CU.
// smem layout (halves): [0,4096) kbuf0, [4096,8192) kbuf1,
//                       [8192,12288) vbuf0, [12288,16384) vbuf1.
// ---------------------------------------------------------------------------
__global__ __launch_bounds__(256, 2) void attn_kernel(
    const _Float16* __restrict__ Qp, const _Float16* __restrict__ Kp,
    const _Float16* __restrict__ Vt, _Float16* __restrict__ Of, int bofs)
{
    int b = blockIdx.x + bofs;           // 0..511
    int slot = b >> 3;                   // 0..63
    int nh = (b & 7) * 4 + (slot & 3);   // XCD swizzle: 4 heads per XCD in L2
    int qt = slot >> 2;                  // 0..15 (128-row q tile)
    int n = nh >> 4, h = nh & 15;
    int t = threadIdx.x;
    int lane = t & 63, wid = t >> 6;
    int l31 = lane & 31, h5 = lane >> 5;

    __shared__ __align__(16) _Float16 smem[4 * 4096];   // 32 KB

    const _Float16* Kb = Kp + (size_t)nh * SS * DD;
    const _Float16* Vb = Vt + (size_t)nh * DD * SS;

    // Q B-fragments, loaded once: n=q=l31 (row), k=d = c*16 + h5*8 + j
    const _Float16* Qb = Qp + ((size_t)nh * SS + qt * 128 + wid * 32 + l31) * DD;
    half8 qf[4];
    #pragma unroll
    for (int c = 0; c < 4; ++c)
        qf[c] = *(const half8*)(Qb + c * 16 + h5 * 8);

    // per-lane fragment read offsets (halves), row l31, col c*16+h5*8
    int aoff[4];
    #pragma unroll
    for (int c = 0; c < 4; ++c)
        aoff[c] = swz64(l31, c * 16 + h5 * 8);

    // ones B-fragment for the row-sum MFMA
    half8 ones = { (_Float16)1.f, (_Float16)1.f, (_Float16)1.f, (_Float16)1.f,
                   (_Float16)1.f, (_Float16)1.f, (_Float16)1.f, (_Float16)1.f };

    // staging map: slot s in [0,512): row = s>>3, colg = s&7 (8 half8s/row)
    int sr = t >> 3, sc = (t & 7) * 8;
    int soff0 = swz64(sr, sc), soff1 = swz64(sr + 32, sc);

    // ---- prologue: stage tile kb=0 into buffer 0
    {
        half8 k0 = *(const half8*)(Kb + (size_t)sr * DD + sc);
        half8 k1 = *(const half8*)(Kb + (size_t)(sr + 32) * DD + sc);
        half8 v0 = *(const half8*)(Vb + (size_t)sr * SS + sc);
        half8 v1 = *(const half8*)(Vb + (size_t)(sr + 32) * SS + sc);
        *(half8*)(&smem[soff0]) = k0;
        *(half8*)(&smem[soff1]) = k1;
        *(half8*)(&smem[8192 + soff0]) = v0;
        *(half8*)(&smem[8192 + soff1]) = v1;
    }
    __syncthreads();

    floatx16 oacc0 = {}, oacc1 = {};   // O for d-tiles 0,1
    floatx16 sacc  = {};               // row sums via ones-MFMA

    int p = 0;
    for (int kb = 0; kb < SS; kb += KT, p ^= 1) {
        // ---- issue global loads for tile t+1 (wrap at end: dummy, unused)
        int kn = (kb + KT) & (SS - 1);
        half8 sk0 = *(const half8*)(Kb + (size_t)(kn + sr) * DD + sc);
        half8 sk1 = *(const half8*)(Kb + (size_t)(kn + sr + 32) * DD + sc);
        half8 sv0 = *(const half8*)(Vb + (size_t)sr * SS + kn + sc);
        half8 sv1 = *(const half8*)(Vb + (size_t)(sr + 32) * SS + kn + sc);

        const _Float16* base = smem + (p << 12);   // kbuf[p]

        // ---- S^T = K Q^T for both 32-key subtiles: D[key][q]
        floatx16 s0 = {}, s1 = {};
        #pragma unroll
        for (int c = 0; c < 4; ++c) {
            half8 kf0 = *(const half8*)(base + aoff[c]);          // row l31
            half8 kf1 = *(const half8*)(base + aoff[c] + 2048);   // row l31+32
            s0 = __builtin_amdgcn_mfma_f32_32x32x16_f16(kf0, qf[c], s0, 0, 0, 0);
            s1 = __builtin_amdgcn_mfma_f32_32x32x16_f16(kf1, qf[c], s1, 0, 0, 0);
        }

        // ---- exp2 + pack + permlane redistribution -> PV A-frags.
        // (r17 numerics: exp2f with fmin clamp, exactly as the passing r17)
        half8 pf[4];
        #pragma unroll
        for (int kt2 = 0; kt2 < 2; ++kt2) {
            const floatx16& sv = kt2 ? s1 : s0;
            unsigned int w0, w1, w2, w3, w4, w5, w6, w7;
            {
                float e0 = exp2f(fminf(sv[0], 50.f)), e1 = exp2f(fminf(sv[1], 50.f));
                float e2 = exp2f(fminf(sv[2], 50.f)), e3 = exp2f(fminf(sv[3], 50.f));
                w0 = pkrtz_u32(e0, e1); w1 = pkrtz_u32(e2, e3);
            }
            {
                float e0 = exp2f(fminf(sv[4], 50.f)), e1 = exp2f(fminf(sv[5], 50.f));
                float e2 = exp2f(fminf(sv[6], 50.f)), e3 = exp2f(fminf(sv[7], 50.f));
                w2 = pkrtz_u32(e0, e1); w3 = pkrtz_u32(e2, e3);
            }
            {
                float e0 = exp2f(fminf(sv[8], 50.f)), e1 = exp2f(fminf(sv[9], 50.f));
                float e2 = exp2f(fminf(sv[10], 50.f)), e3 = exp2f(fminf(sv[11], 50.f));
                w4 = pkrtz_u32(e0, e1); w5 = pkrtz_u32(e2, e3);
            }
            {
                float e0 = exp2f(fminf(sv[12], 50.f)), e1 = exp2f(fminf(sv[13], 50.f));
                float e2 = exp2f(fminf(sv[14], 50.f)), e3 = exp2f(fminf(sv[15], 50.f));
                w6 = pkrtz_u32(e0, e1); w7 = pkrtz_u32(e2, e3);
            }
            asm("v_permlane32_swap_b32 %0, %1" : "+v"(w0), "+v"(w2));
            asm("v_permlane32_swap_b32 %0, %1" : "+v"(w1), "+v"(w3));
            asm("v_permlane32_swap_b32 %0, %1" : "+v"(w4), "+v"(w6));
            asm("v_permlane32_swap_b32 %0, %1" : "+v"(w5), "+v"(w7));
            uint4 ua = {w0, w1, w2, w3};
            uint4 ub = {w4, w5, w6, w7};
            pf[kt2 * 2 + 0] = __builtin_bit_cast(half8, ua);
            pf[kt2 * 2 + 1] = __builtin_bit_cast(half8, ub);
        }

        // ---- O += P V ; row-sum += P * ones. B = V[key][d] from vbuf[d][key].
        #pragma unroll
        for (int c = 0; c < 4; ++c) {
            half8 vf0 = *(const half8*)(base + 8192 + aoff[c]);
            half8 vf1 = *(const half8*)(base + 8192 + aoff[c] + 2048);
            oacc0 = __builtin_amdgcn_mfma_f32_32x32x16_f16(pf[c], vf0, oacc0, 0, 0, 0);
            oacc1 = __builtin_amdgcn_mfma_f32_32x32x16_f16(pf[c], vf1, oacc1, 0, 0, 0);
            sacc  = __builtin_amdgcn_mfma_f32_32x32x16_f16(pf[c], ones, sacc, 0, 0, 0);
        }

        // ---- write staged tile t+1 into the other buffer, then barrier
        {
            int poff = ((p ^ 1) << 12);
            *(half8*)(&smem[poff + soff0]) = sk0;
            *(half8*)(&smem[poff + soff1]) = sk1;
            *(half8*)(&smem[poff + 8192 + soff0]) = sv0;
            *(half8*)(&smem[poff + 8192 + soff1]) = sv1;
        }
        __syncthreads();
    }

    // ---- normalize into smem[0..8192) ([128][64] swizzled), then store Of
    // as full 128B lines (4 b128/thread). Exact divide (r17 numerics).
    _Float16* obuf = smem;
    #pragma unroll
    for (int r = 0; r < 16; ++r) {
        float linv = 1.f / sacc[r];
        int qrow = wid * 32 + (r & 3) + 8 * (r >> 2) + 4 * h5;
        obuf[swz64(qrow, l31)]      = (_Float16)(oacc0[r] * linv);
        obuf[swz64(qrow, 32 + l31)] = (_Float16)(oacc1[r] * linv);
    }
    __syncthreads();
    {
        int orow = t >> 2, ocol = (t & 3) * 16;
        _Float16* Ob = Of + ((size_t)n * SS + qt * 128) * EE + h * DD;
        #pragma unroll
        for (int g = 0; g < 2; ++g) {
            int rr = g * 64 + orow;
            *(half8*)(Ob + (size_t)rr * EE + ocol)
                = *(const half8*)(&obuf[swz64(rr, ocol)]);
            *(half8*)(Ob + (size_t)rr * EE + ocol + 8)
                = *(const half8*)(&obuf[swz64(rr, ocol + 8)]);
        }
    }
}

// ---------------------------------------------------------------------------
// Kernel 3 (r14, unchanged): out = O @ Wo.T + bo, 64x128-tile MFMA GEMM.
// 512 blocks = 2 blocks/CU; XCD swizzle pins Of m-tile per XCD L2.
// ---------------------------------------------------------------------------
__global__ __launch_bounds__(256, 2) void oproj_kernel(
    const _Float16* __restrict__ Of, const _Float16* __restrict__ Wf,
    const float* __restrict__ bo, float* __restrict__ out)
{
    int b = blockIdx.x;             // 0..511
    int mb = b & 63, nb = b >> 6;   // XCD = b%8 = mb%8 -> Of tile XCD-local
    int t = threadIdx.x, lane = t & 63, wid = t >> 6;
    int wm = wid >> 1, wn = wid & 1;
    int lr = lane & 15, lg = lane >> 4;
    int m0 = mb * 64, n0 = nb * 128;

    __shared__ __align__(16) _Float16 As[2][64][72];    // 2 x 9 KB
    __shared__ __align__(16) _Float16 Bs[2][128][72];   // 2 x 18 KB

    // staging maps: A: thread t covers row t>>2, 2 half8s at col (t&3)*16.
    //               B: thread t covers row t>>1, 4 half8s at col (t&1)*32.
    int arow = t >> 2, acol = (t & 3) * 16;
    int brow = t >> 1, bcol = (t & 1) * 32;
    const _Float16* Ag = Of + (size_t)(m0 + arow) * EE + acol;
    const _Float16* Bg = Wf + (size_t)(n0 + brow) * EE + bcol;

    floatx4 acc[2][4];
    #pragma unroll
    for (int sm = 0; sm < 2; ++sm)
        #pragma unroll
        for (int sn = 0; sn < 4; ++sn) acc[sm][sn] = (floatx4){0.f, 0.f, 0.f, 0.f};

    // ---- prologue: stage kb=0 into buffer 0
    #pragma unroll
    for (int j = 0; j < 2; ++j)
        *(half8*)(&As[0][arow][acol + j * 8]) = *(const half8*)(Ag + j * 8);
    #pragma unroll
    for (int j = 0; j < 4; ++j)
        *(half8*)(&Bs[0][brow][bcol + j * 8]) = *(const half8*)(Bg + j * 8);
    __syncthreads();

    int p = 0;
    for (int kb = 0; kb < EE; kb += 64, p ^= 1) {
        int kn = kb + 64;
        // ---- issue next chunk's global loads
        half8 sa[2], sb[4];
        if (kn < EE) {
            #pragma unroll
            for (int j = 0; j < 2; ++j) sa[j] = *(const half8*)(Ag + kn + j * 8);
            #pragma unroll
            for (int j = 0; j < 4; ++j) sb[j] = *(const half8*)(Bg + kn + j * 8);
        }
        // ---- compute on buffer p: 2 k-subchunks of 32
        #pragma unroll
        for (int kk = 0; kk < 2; ++kk) {
            half8 af[2], bf[4];
            #pragma unroll
            for (int s = 0; s < 2; ++s)
                af[s] = *(const half8*)(&As[p][wm * 32 + s * 16 + lr][kk * 32 + lg * 8]);
            #pragma unroll
            for (int s = 0; s < 4; ++s)
                bf[s] = *(const half8*)(&Bs[p][wn * 64 + s * 16 + lr][kk * 32 + lg * 8]);
            #pragma unroll
            for (int sm = 0; sm < 2; ++sm)
                #pragma unroll
                for (int sn = 0; sn < 4; ++sn)
                    acc[sm][sn] = __builtin_amdgcn_mfma_f32_16x16x32_f16(
                        af[sm], bf[sn], acc[sm][sn], 0, 0, 0);
        }
        // ---- write staged chunk into the other buffer
        if (kn < EE) {
            #pragma unroll
            for (int j = 0; j < 2; ++j)
                *(half8*)(&As[p ^ 1][arow][acol + j * 8]) = sa[j];
            #pragma unroll
            for (int j = 0; j < 4; ++j)
                *(half8*)(&Bs[p ^ 1][brow][bcol + j * 8]) = sb[j];
        }
        __syncthreads();
    }

    // ---- epilogue: C/D col = lr (n), row = lg*4+r (m)
    #pragma unroll
    for (int sn = 0; sn < 4; ++sn) {
        int nn = n0 + wn * 64 + sn * 16 + lr;
        float bn = bo[nn];
        #pragma unroll
        for (int sm = 0; sm < 2; ++sm) {
            #pragma unroll
            for (int r = 0; r < 4; ++r)
                out[(size_t)(m0 + wm * 32 + sm * 16 + lg * 4 + r) * EE + nn]
                    = acc[sm][sn][r] + bn;
        }
    }
}

// ---------------------------------------------------------------------------
extern "C" void kernel_launch(void* const* d_in, const int* in_sizes, int n_in,
                              void* d_out, int out_size, void* d_ws, size_t ws_size,
                              hipStream_t stream)
{
    const float* Q  = (const float*)d_in[0];
    const float* K  = (const float*)d_in[1];
    const float* V  = (const float*)d_in[2];
    const float* Wq = (const float*)d_in[3];
    const float* Wk = (const float*)d_in[4];
    const float* Wv = (const float*)d_in[5];
    const float* Wo = (const float*)d_in[6];
    const float* bo = (const float*)d_in[7];
    float* out = (float*)d_out;

    const size_t NSE = (size_t)NB * SS * EE;   // 4.19M elements
    _Float16* Qp = (_Float16*)d_ws;  // [nh][s][d] pre-scaled   8.4 MB
    _Float16* Kp = Qp + NSE;         // [nh][s][d]              8.4 MB
    _Float16* Vt = Kp + NSE;         // [nh][d][s] transposed   8.4 MB
    _Float16* Of = Vt + NSE;         // [n][s][e] f16           8.4 MB
    _Float16* Wf = Of + NSE;         // [1024][1024] f16        2.1 MB (~36 MB)

    proj_kernel<<<1024, 256, 0, stream>>>(Q, K, V, Wq, Wk, Wv, Wo, Qp, Kp, Vt, Wf);
    // attn split into two half-grid dispatches (~36us each) so proj/oproj
    // surface in rocprof's top-5 next round (observability, zero numerics).
    attn_kernel<<<256, 256, 0, stream>>>(Qp, Kp, Vt, Of, 0);
    attn_kernel<<<256, 256, 0, stream>>>(Qp, Kp, Vt, Of, 256);
    oproj_kernel<<<512, 256, 0, stream>>>(Of, Wf, bo, out);
}

// Round 10
// 206.339 us; speedup vs baseline: 1.0992x; 1.0992x over previous
//
#include <hip/hip_runtime.h>
#include <hip/hip_bf16.h>

// Problem constants
#define NB 2
#define SS 2048
#define EE 1024
#define HH 16
#define DD 64
#define NHD (NB*HH)   // 32 (n,h) pairs
#define KT 64         // keys per flash tile

// fold softmax scale (1/sqrt(1024)) and log2(e) into Q' so P = exp2(S')
#define QSCALE 0.04508422002777998f

typedef _Float16 half8 __attribute__((ext_vector_type(8)));
typedef float floatx4 __attribute__((ext_vector_type(4)));
typedef float floatx16 __attribute__((ext_vector_type(16)));

__device__ __forceinline__ half8 cvt8(const float* p) {
    float4 x = *(const float4*)p;
    float4 y = *(const float4*)(p + 4);
    half8 h = { (_Float16)x.x, (_Float16)x.y, (_Float16)x.z, (_Float16)x.w,
                (_Float16)y.x, (_Float16)y.y, (_Float16)y.z, (_Float16)y.w };
    return h;
}

// packed f32x2 -> f16x2 (RTZ) returning raw u32
__device__ __forceinline__ unsigned int pkrtz_u32(float a, float b) {
    return __builtin_bit_cast(unsigned int, __builtin_amdgcn_cvt_pkrtz(a, b));
}

// exp2 via plain VALU polynomial (NO v_exp_f32).
// HISTORY (r18/r20): native v_exp_f32 - builtin AND inline-asm-with-nop -
// produces absmax ~7e-3 (vs 4.9e-4 passing); mechanism unexplained by 1-ulp
// accuracy, presumed gfx950 TRANS-write hazard. DO NOT use v_exp_f32 here.
// OCML exp2f is accurate but ~30 VALU instrs (measured r19: ~900 cyc of the
// 1370 VALU cyc/wave-iter). This: 11 interlocked VALU ops, zero hazard
// surface. P is f16-RTZ-quantized right after (9.8e-4 rel), so the
// degree-4 Taylor remainder (<=4.2e-5 rel on |f|<=0.5) is negligible.
// ldexp via int exponent-add is valid: p in [0.707,1.414] (normal), clamp
// +-30 keeps result exponent in [96,157].
__device__ __forceinline__ float poly_exp2(float x) {
    x = fminf(fmaxf(x, -30.f), 30.f);        // v_med3_f32
    float n = __builtin_rintf(x);            // v_rndne_f32
    float f = x - n;                         // f in [-0.5, 0.5]
    float p = 0.0096179669f;                 // ln2^4/24
    p = __builtin_fmaf(p, f, 0.0555041086f); // ln2^3/6
    p = __builtin_fmaf(p, f, 0.2402265069f); // ln2^2/2
    p = __builtin_fmaf(p, f, 0.6931471806f); // ln2
    p = __builtin_fmaf(p, f, 1.0f);
    return __builtin_bit_cast(float,
        __builtin_bit_cast(int, p) + ((int)n << 23));
}

// XOR-swizzled index (in halves) for [R][64-half] f16 LDS tiles (R<=128).
// 16B groups: group' = group ^ (row&7). Keeps b128 alignment (r13-verified).
__device__ __forceinline__ int swz64(int row, int colh) {
    return (row << 6) + ((((colh >> 3) ^ (row & 7)) << 3) | (colh & 7));
}

// ---------------------------------------------------------------------------
// Kernel 1 (r17, unchanged): QKV projection via MFMA + absorbed Wo f32->f16.
// All outputs route through the swizzled LDS tile -> 128B-line stores.
// Outputs: Q' f16 [nh][s][d] pre-scaled, K' f16 [nh][s][d], V' f16 [nh][d][s],
//          Wf f16 [1024][1024].
// ---------------------------------------------------------------------------
__global__ __launch_bounds__(256) void proj_kernel(
    const float* __restrict__ Q, const float* __restrict__ K, const float* __restrict__ V,
    const float* __restrict__ Wq, const float* __restrict__ Wk, const float* __restrict__ Wv,
    const float* __restrict__ Wo,
    _Float16* __restrict__ Qp, _Float16* __restrict__ Kp, _Float16* __restrict__ Vt,
    _Float16* __restrict__ Wf)
{
    int t = threadIdx.x, lane = t & 63, wid = t >> 6;
    int lr = lane & 15, lg = lane >> 4;
    int b = blockIdx.x;             // 0..1023
    int nh = b >> 5, st = b & 31;   // head-pair, s-tile (64 rows)
    int n = nh >> 4, h = nh & 15;

    // absorbed wconv: 128 threads x 8 elems = 1KB of Wo per block
    if (t < 128) {
        int i = b * 1024 + t * 8;
        *(half8*)(Wf + i) = cvt8(Wo + i);
    }

    __shared__ __align__(16) _Float16 vt[64 * 64];   // 8 KB, swizzled

    // A-fragment rows: s = st*64 + wid*16 + lr  (m = lane&15)
    const size_t xoff = ((size_t)n * SS + st * 64 + wid * 16 + lr) * EE
                        + (size_t)h * DD + lg * 8;

    // coalesced output map: thread t covers row t>>2, 2x16B at col (t&3)*16
    int orow = t >> 2, ocol = (t & 3) * 16;
    _Float16* qdst = Qp + ((size_t)nh * SS + st * 64 + orow) * DD + ocol;
    _Float16* kdst = Kp + ((size_t)nh * SS + st * 64 + orow) * DD + ocol;
    _Float16* vdst = Vt + ((size_t)nh * DD + orow) * SS + st * 64 + ocol;

    const float* tens[3] = {Q, K, V};
    const float* wts[3]  = {Wq, Wk, Wv};

    #pragma unroll
    for (int x = 0; x < 3; ++x) {
        const float* Xr = tens[x] + xoff;
        half8 a0 = cvt8(Xr);
        half8 a1 = cvt8(Xr + 32);
        floatx4 acc[4];
        #pragma unroll
        for (int ns = 0; ns < 4; ++ns) {
            const float* Wr = wts[x] + (size_t)(ns * 16 + lr) * DD + lg * 8;
            half8 b0 = cvt8(Wr);
            half8 b1 = cvt8(Wr + 32);
            floatx4 c = (floatx4){0.f, 0.f, 0.f, 0.f};
            c = __builtin_amdgcn_mfma_f32_16x16x32_f16(a0, b0, c, 0, 0, 0);
            c = __builtin_amdgcn_mfma_f32_16x16x32_f16(a1, b1, c, 0, 0, 0);
            acc[ns] = c;
        }
        if (x) __syncthreads();   // previous pass's vt reads done
        if (x < 2) {
            // Q/K: vt[s_local][d], s_local = wid*16+lg*4+r, d = ns*16+lr
            float s = (x == 0) ? QSCALE : 1.0f;
            #pragma unroll
            for (int ns = 0; ns < 4; ++ns)
                #pragma unroll
                for (int r = 0; r < 4; ++r)
                    vt[swz64(wid * 16 + lg * 4 + r, ns * 16 + lr)]
                        = (_Float16)(acc[ns][r] * s);
        } else {
            // V transpose: vt[d][s_local]
            #pragma unroll
            for (int ns = 0; ns < 4; ++ns)
                #pragma unroll
                for (int r = 0; r < 4; ++r)
                    vt[swz64(ns * 16 + lr, wid * 16 + lg * 4 + r)]
                        = (_Float16)(acc[ns][r]);
        }
        __syncthreads();
        _Float16* dst = (x == 0) ? qdst : (x == 1) ? kdst : vdst;
        *(half8*)dst       = *(const half8*)(&vt[swz64(orow, ocol)]);
        *(half8*)(dst + 8) = *(const half8*)(&vt[swz64(orow, ocol + 8)]);
    }
}

// ---------------------------------------------------------------------------
// Kernel 2 (r21): flash MFMA attention, 32x32 MFMA + in-register P.
// SINGLE-VARIABLE vs passing r19: exp2f (OCML wrapper, ~30 instrs) ->
// poly_exp2 (11 interlocked VALU ops, no TRANS instruction). See poly_exp2
// comment for the r18/r20 native-exp failure history.
// r19 measured ~1370 VALU cyc/wave-iter; poly cuts exp+clamp ~950 -> ~350.
// 32x32 frag maps (r16-verified): A/B[m][k]: m=lane&31, k=(lane>>5)*8+j.
// C/D: col=lane&31, row=(r&3)+8*(r>>2)+4*(lane>>5).
// GRID: 512 = 32 nh x 16 q-tiles (128 rows). LDS 32KB -> 2 blocks/CU.
// smem layout (halves): [0,4096) kbuf0, [4096,8192) kbuf1,
//                       [8192,12288) vbuf0, [12288,16384) vbuf1.
// ---------------------------------------------------------------------------
__global__ __launch_bounds__(256, 2) void attn_kernel(
    const _Float16* __restrict__ Qp, const _Float16* __restrict__ Kp,
    const _Float16* __restrict__ Vt, _Float16* __restrict__ Of)
{
    int b = blockIdx.x;                  // 0..511
    int slot = b >> 3;                   // 0..63
    int nh = (b & 7) * 4 + (slot & 3);   // XCD swizzle: 4 heads per XCD in L2
    int qt = slot >> 2;                  // 0..15 (128-row q tile)
    int n = nh >> 4, h = nh & 15;
    int t = threadIdx.x;
    int lane = t & 63, wid = t >> 6;
    int l31 = lane & 31, h5 = lane >> 5;

    __shared__ __align__(16) _Float16 smem[4 * 4096];   // 32 KB

    const _Float16* Kb = Kp + (size_t)nh * SS * DD;
    const _Float16* Vb = Vt + (size_t)nh * DD * SS;

    // Q B-fragments, loaded once: n=q=l31 (row), k=d = c*16 + h5*8 + j
    const _Float16* Qb = Qp + ((size_t)nh * SS + qt * 128 + wid * 32 + l31) * DD;
    half8 qf[4];
    #pragma unroll
    for (int c = 0; c < 4; ++c)
        qf[c] = *(const half8*)(Qb + c * 16 + h5 * 8);

    // per-lane fragment read offsets (halves), row l31, col c*16+h5*8
    int aoff[4];
    #pragma unroll
    for (int c = 0; c < 4; ++c)
        aoff[c] = swz64(l31, c * 16 + h5 * 8);

    // ones B-fragment for the row-sum MFMA
    half8 ones = { (_Float16)1.f, (_Float16)1.f, (_Float16)1.f, (_Float16)1.f,
                   (_Float16)1.f, (_Float16)1.f, (_Float16)1.f, (_Float16)1.f };

    // staging map: slot s in [0,512): row = s>>3, colg = s&7 (8 half8s/row)
    int sr = t >> 3, sc = (t & 7) * 8;
    int soff0 = swz64(sr, sc), soff1 = swz64(sr + 32, sc);

    // ---- prologue: stage tile kb=0 into buffer 0
    {
        half8 k0 = *(const half8*)(Kb + (size_t)sr * DD + sc);
        half8 k1 = *(const half8*)(Kb + (size_t)(sr + 32) * DD + sc);
        half8 v0 = *(const half8*)(Vb + (size_t)sr * SS + sc);
        half8 v1 = *(const half8*)(Vb + (size_t)(sr + 32) * SS + sc);
        *(half8*)(&smem[soff0]) = k0;
        *(half8*)(&smem[soff1]) = k1;
        *(half8*)(&smem[8192 + soff0]) = v0;
        *(half8*)(&smem[8192 + soff1]) = v1;
    }
    __syncthreads();

    floatx16 oacc0 = {}, oacc1 = {};   // O for d-tiles 0,1
    floatx16 sacc  = {};               // row sums via ones-MFMA

    int p = 0;
    for (int kb = 0; kb < SS; kb += KT, p ^= 1) {
        // ---- issue global loads for tile t+1 (wrap at end: dummy, unused)
        int kn = (kb + KT) & (SS - 1);
        half8 sk0 = *(const half8*)(Kb + (size_t)(kn + sr) * DD + sc);
        half8 sk1 = *(const half8*)(Kb + (size_t)(kn + sr + 32) * DD + sc);
        half8 sv0 = *(const half8*)(Vb + (size_t)sr * SS + kn + sc);
        half8 sv1 = *(const half8*)(Vb + (size_t)(sr + 32) * SS + kn + sc);

        const _Float16* base = smem + (p << 12);   // kbuf[p]

        // ---- S^T = K Q^T for both 32-key subtiles: D[key][q]
        floatx16 s0 = {}, s1 = {};
        #pragma unroll
        for (int c = 0; c < 4; ++c) {
            half8 kf0 = *(const half8*)(base + aoff[c]);          // row l31
            half8 kf1 = *(const half8*)(base + aoff[c] + 2048);   // row l31+32
            s0 = __builtin_amdgcn_mfma_f32_32x32x16_f16(kf0, qf[c], s0, 0, 0, 0);
            s1 = __builtin_amdgcn_mfma_f32_32x32x16_f16(kf1, qf[c], s1, 0, 0, 0);
        }

        // ---- exp2 (poly, plain VALU) + pack + permlane -> PV A-frags.
        half8 pf[4];
        #pragma unroll
        for (int kt2 = 0; kt2 < 2; ++kt2) {
            const floatx16& sv = kt2 ? s1 : s0;
            unsigned int w0, w1, w2, w3, w4, w5, w6, w7;
            {
                float e0 = poly_exp2(sv[0]), e1 = poly_exp2(sv[1]);
                float e2 = poly_exp2(sv[2]), e3 = poly_exp2(sv[3]);
                w0 = pkrtz_u32(e0, e1); w1 = pkrtz_u32(e2, e3);
            }
            {
                float e0 = poly_exp2(sv[4]), e1 = poly_exp2(sv[5]);
                float e2 = poly_exp2(sv[6]), e3 = poly_exp2(sv[7]);
                w2 = pkrtz_u32(e0, e1); w3 = pkrtz_u32(e2, e3);
            }
            {
                float e0 = poly_exp2(sv[8]), e1 = poly_exp2(sv[9]);
                float e2 = poly_exp2(sv[10]), e3 = poly_exp2(sv[11]);
                w4 = pkrtz_u32(e0, e1); w5 = pkrtz_u32(e2, e3);
            }
            {
                float e0 = poly_exp2(sv[12]), e1 = poly_exp2(sv[13]);
                float e2 = poly_exp2(sv[14]), e3 = poly_exp2(sv[15]);
                w6 = pkrtz_u32(e0, e1); w7 = pkrtz_u32(e2, e3);
            }
            asm("v_permlane32_swap_b32 %0, %1" : "+v"(w0), "+v"(w2));
            asm("v_permlane32_swap_b32 %0, %1" : "+v"(w1), "+v"(w3));
            asm("v_permlane32_swap_b32 %0, %1" : "+v"(w4), "+v"(w6));
            asm("v_permlane32_swap_b32 %0, %1" : "+v"(w5), "+v"(w7));
            uint4 ua = {w0, w1, w2, w3};
            uint4 ub = {w4, w5, w6, w7};
            pf[kt2 * 2 + 0] = __builtin_bit_cast(half8, ua);
            pf[kt2 * 2 + 1] = __builtin_bit_cast(half8, ub);
        }

        // ---- O += P V ; row-sum += P * ones. B = V[key][d] from vbuf[d][key].
        #pragma unroll
        for (int c = 0; c < 4; ++c) {
            half8 vf0 = *(const half8*)(base + 8192 + aoff[c]);
            half8 vf1 = *(const half8*)(base + 8192 + aoff[c] + 2048);
            oacc0 = __builtin_amdgcn_mfma_f32_32x32x16_f16(pf[c], vf0, oacc0, 0, 0, 0);
            oacc1 = __builtin_amdgcn_mfma_f32_32x32x16_f16(pf[c], vf1, oacc1, 0, 0, 0);
            sacc  = __builtin_amdgcn_mfma_f32_32x32x16_f16(pf[c], ones, sacc, 0, 0, 0);
        }

        // ---- write staged tile t+1 into the other buffer, then barrier
        {
            int poff = ((p ^ 1) << 12);
            *(half8*)(&smem[poff + soff0]) = sk0;
            *(half8*)(&smem[poff + soff1]) = sk1;
            *(half8*)(&smem[poff + 8192 + soff0]) = sv0;
            *(half8*)(&smem[poff + 8192 + soff1]) = sv1;
        }
        __syncthreads();
    }

    // ---- normalize into smem[0..8192) ([128][64] swizzled), then store Of
    // as full 128B lines (4 b128/thread). Exact divide (r19 numerics).
    _Float16* obuf = smem;
    #pragma unroll
    for (int r = 0; r < 16; ++r) {
        float linv = 1.f / sacc[r];
        int qrow = wid * 32 + (r & 3) + 8 * (r >> 2) + 4 * h5;
        obuf[swz64(qrow, l31)]      = (_Float16)(oacc0[r] * linv);
        obuf[swz64(qrow, 32 + l31)] = (_Float16)(oacc1[r] * linv);
    }
    __syncthreads();
    {
        int orow = t >> 2, ocol = (t & 3) * 16;
        _Float16* Ob = Of + ((size_t)n * SS + qt * 128) * EE + h * DD;
        #pragma unroll
        for (int g = 0; g < 2; ++g) {
            int rr = g * 64 + orow;
            *(half8*)(Ob + (size_t)rr * EE + ocol)
                = *(const half8*)(&obuf[swz64(rr, ocol)]);
            *(half8*)(Ob + (size_t)rr * EE + ocol + 8)
                = *(const half8*)(&obuf[swz64(rr, ocol + 8)]);
        }
    }
}

// ---------------------------------------------------------------------------
// Kernel 3 (r14, unchanged): out = O @ Wo.T + bo, 64x128-tile MFMA GEMM.
// 512 blocks = 2 blocks/CU; XCD swizzle pins Of m-tile per XCD L2.
// ---------------------------------------------------------------------------
__global__ __launch_bounds__(256, 2) void oproj_kernel(
    const _Float16* __restrict__ Of, const _Float16* __restrict__ Wf,
    const float* __restrict__ bo, float* __restrict__ out)
{
    int b = blockIdx.x;             // 0..511
    int mb = b & 63, nb = b >> 6;   // XCD = b%8 = mb%8 -> Of tile XCD-local
    int t = threadIdx.x, lane = t & 63, wid = t >> 6;
    int wm = wid >> 1, wn = wid & 1;
    int lr = lane & 15, lg = lane >> 4;
    int m0 = mb * 64, n0 = nb * 128;

    __shared__ __align__(16) _Float16 As[2][64][72];    // 2 x 9 KB
    __shared__ __align__(16) _Float16 Bs[2][128][72];   // 2 x 18 KB

    // staging maps: A: thread t covers row t>>2, 2 half8s at col (t&3)*16.
    //               B: thread t covers row t>>1, 4 half8s at col (t&1)*32.
    int arow = t >> 2, acol = (t & 3) * 16;
    int brow = t >> 1, bcol = (t & 1) * 32;
    const _Float16* Ag = Of + (size_t)(m0 + arow) * EE + acol;
    const _Float16* Bg = Wf + (size_t)(n0 + brow) * EE + bcol;

    floatx4 acc[2][4];
    #pragma unroll
    for (int sm = 0; sm < 2; ++sm)
        #pragma unroll
        for (int sn = 0; sn < 4; ++sn) acc[sm][sn] = (floatx4){0.f, 0.f, 0.f, 0.f};

    // ---- prologue: stage kb=0 into buffer 0
    #pragma unroll
    for (int j = 0; j < 2; ++j)
        *(half8*)(&As[0][arow][acol + j * 8]) = *(const half8*)(Ag + j * 8);
    #pragma unroll
    for (int j = 0; j < 4; ++j)
        *(half8*)(&Bs[0][brow][bcol + j * 8]) = *(const half8*)(Bg + j * 8);
    __syncthreads();

    int p = 0;
    for (int kb = 0; kb < EE; kb += 64, p ^= 1) {
        int kn = kb + 64;
        // ---- issue next chunk's global loads
        half8 sa[2], sb[4];
        if (kn < EE) {
            #pragma unroll
            for (int j = 0; j < 2; ++j) sa[j] = *(const half8*)(Ag + kn + j * 8);
            #pragma unroll
            for (int j = 0; j < 4; ++j) sb[j] = *(const half8*)(Bg + kn + j * 8);
        }
        // ---- compute on buffer p: 2 k-subchunks of 32
        #pragma unroll
        for (int kk = 0; kk < 2; ++kk) {
            half8 af[2], bf[4];
            #pragma unroll
            for (int s = 0; s < 2; ++s)
                af[s] = *(const half8*)(&As[p][wm * 32 + s * 16 + lr][kk * 32 + lg * 8]);
            #pragma unroll
            for (int s = 0; s < 4; ++s)
                bf[s] = *(const half8*)(&Bs[p][wn * 64 + s * 16 + lr][kk * 32 + lg * 8]);
            #pragma unroll
            for (int sm = 0; sm < 2; ++sm)
                #pragma unroll
                for (int sn = 0; sn < 4; ++sn)
                    acc[sm][sn] = __builtin_amdgcn_mfma_f32_16x16x32_f16(
                        af[sm], bf[sn], acc[sm][sn], 0, 0, 0);
        }
        // ---- write staged chunk into the other buffer
        if (kn < EE) {
            #pragma unroll
            for (int j = 0; j < 2; ++j)
                *(half8*)(&As[p ^ 1][arow][acol + j * 8]) = sa[j];
            #pragma unroll
            for (int j = 0; j < 4; ++j)
                *(half8*)(&Bs[p ^ 1][brow][bcol + j * 8]) = sb[j];
        }
        __syncthreads();
    }

    // ---- epilogue: C/D col = lr (n), row = lg*4+r (m)
    #pragma unroll
    for (int sn = 0; sn < 4; ++sn) {
        int nn = n0 + wn * 64 + sn * 16 + lr;
        float bn = bo[nn];
        #pragma unroll
        for (int sm = 0; sm < 2; ++sm) {
            #pragma unroll
            for (int r = 0; r < 4; ++r)
                out[(size_t)(m0 + wm * 32 + sm * 16 + lg * 4 + r) * EE + nn]
                    = acc[sm][sn][r] + bn;
        }
    }
}

// ---------------------------------------------------------------------------
extern "C" void kernel_launch(void* const* d_in, const int* in_sizes, int n_in,
                              void* d_out, int out_size, void* d_ws, size_t ws_size,
                              hipStream_t stream)
{
    const float* Q  = (const float*)d_in[0];
    const float* K  = (const float*)d_in[1];
    const float* V  = (const float*)d_in[2];
    const float* Wq = (const float*)d_in[3];
    const float* Wk = (const float*)d_in[4];
    const float* Wv = (const float*)d_in[5];
    const float* Wo = (const float*)d_in[6];
    const float* bo = (const float*)d_in[7];
    float* out = (float*)d_out;

    const size_t NSE = (size_t)NB * SS * EE;   // 4.19M elements
    _Float16* Qp = (_Float16*)d_ws;  // [nh][s][d] pre-scaled   8.4 MB
    _Float16* Kp = Qp + NSE;         // [nh][s][d]              8.4 MB
    _Float16* Vt = Kp + NSE;         // [nh][d][s] transposed   8.4 MB
    _Float16* Of = Vt + NSE;         // [n][s][e] f16           8.4 MB
    _Float16* Wf = Of + NSE;         // [1024][1024] f16        2.1 MB (~36 MB)

    proj_kernel<<<1024, 256, 0, stream>>>(Q, K, V, Wq, Wk, Wv, Wo, Qp, Kp, Vt, Wf);
    attn_kernel<<<512, 256, 0, stream>>>(Qp, Kp, Vt, Of);   // 32 nh x 16 qt
    oproj_kernel<<<512, 256, 0, stream>>>(Of, Wf, bo, out);
}